// Round 3
// baseline (353.618 us; speedup 1.0000x reference)
//
#include <hip/hip_runtime.h>
#include <stdint.h>

// HydraAttention on MI355X (gfx950), R8.
// GEMMs: 256x256 tile, 4 waves x (128x128 per-wave output) -> 16 B of LDS
// read per kFLOP (ratio LDS:MFMA = 0.75, MFMA-bound for the first time;
// R5's 2x2 blocking was 1.5 = LDS-bound, measured 38% = serialized bound).
// T3-minimum pipeline: STAGE(t+1); compute(t) [2048 cyc MFMA hides loads];
// vmcnt(0) on 2048-cyc-old loads (free); barrier. Compiler does counted
// lgkm pipelining of frag reads inside the unrolled inner loop.
// All addressing/swizzle/fragment/epilogue conventions identical to the
// verified R5 code. Identity: out = invq[r]*(q @ (Wout*kv_b)^T) + b.

typedef short  short8   __attribute__((ext_vector_type(8)));
typedef float  floatx16 __attribute__((ext_vector_type(16)));

#define NTK 16   // K=1024 / BK=64 k-tiles

__device__ __forceinline__ void async16(const void* g, void* l) {
  __builtin_amdgcn_global_load_lds((const __attribute__((address_space(1))) void*)g,
                                   (__attribute__((address_space(3))) void*)l, 16, 0, 0);
}

__device__ __forceinline__ uint16_t f2bf(float f) {  // RNE fp32->bf16
  union { float f; uint32_t u; } x; x.f = f;
  uint32_t u = x.u;
  return (uint16_t)((u + 0x7fffu + ((u >> 16) & 1u)) >> 16);
}
__device__ __forceinline__ float bf2f(uint16_t h) {
  union { uint32_t u; float f; } x; x.u = ((uint32_t)h) << 16; return x.f;
}
__device__ __forceinline__ uint32_t pack2(float a, float b) {
  return (uint32_t)f2bf(a) | ((uint32_t)f2bf(b) << 16);
}
__device__ __forceinline__ void upk8(uint4 u, float* f) {
  f[0]=bf2f((uint16_t)u.x); f[1]=bf2f((uint16_t)(u.x>>16));
  f[2]=bf2f((uint16_t)u.y); f[3]=bf2f((uint16_t)(u.y>>16));
  f[4]=bf2f((uint16_t)u.z); f[5]=bf2f((uint16_t)(u.z>>16));
  f[6]=bf2f((uint16_t)u.w); f[7]=bf2f((uint16_t)(u.w>>16));
}

// ---------------- fused fp32->bf16 convert of 3 buffers ----------------
__global__ __launch_bounds__(256) void cvt3(
    const float* __restrict__ a, uint16_t* __restrict__ ao, int na,
    const float* __restrict__ b, uint16_t* __restrict__ bo, int nb,
    const float* __restrict__ c, uint16_t* __restrict__ co, int nc) {
  int i = blockIdx.x * 256 + threadIdx.x;
  const float* in; uint16_t* out; int j = i;
  if (j < na) { in = a; out = ao; }
  else {
    j -= na;
    if (j < nb) { in = b; out = bo; }
    else { j -= nb; if (j >= nc) return; in = c; out = co; }
  }
  const float4* p = (const float4*)in;
  float4 u = p[(size_t)j * 2], v = p[(size_t)j * 2 + 1];
  uint4 o;
  o.x = pack2(u.x, u.y); o.y = pack2(u.z, u.w);
  o.z = pack2(v.x, v.y); o.w = pack2(v.z, v.w);
  ((uint4*)out)[j] = o;
}

// Stage one 256x64 K-tile of A and B into buffer (tt)&1.
// Row r staged by 8 threads; source slot pre-swizzled: lane slot
// (l&7)^(l>>3) -> LDS slot p holds source slot p^(r&7).
#define STG(tt, SA, SB) { \
    char* lA_ = (char*)As[(tt) & 1] + wave * 1024; \
    char* lB_ = (char*)Bs[(tt) & 1] + wave * 1024; \
    const size_t ko_ = (size_t)(tt) * 64; \
    _Pragma("unroll") \
    for (int s_ = 0; s_ < 8; s_++) { \
      async16(gA + ko_ + (size_t)s_ * 32 * (SA), lA_ + s_ * 4096); \
      async16(gB + ko_ + (size_t)s_ * 32 * (SB), lB_ + s_ * 4096); \
    } }

// One K-tile of compute: 4 k-steps x (4 A-frags, 4 B-frags, 16 MFMA).
// Read slot = kc ^ (row&7); row&7 == l31&7 for all frag rows.
#define COMPUTE(Ac_, Bc_) \
  _Pragma("unroll") \
  for (int ks = 0; ks < 4; ++ks) { \
    const int so = ((khalf + ks * 2) ^ r7) * 8; \
    short8 af[4], bfr[4]; \
    _Pragma("unroll") \
    for (int mi = 0; mi < 4; mi++) \
      af[mi] = *(const short8*)&(Ac_)[(wm * 128 + mi * 32 + l31) * 64 + so]; \
    _Pragma("unroll") \
    for (int ni = 0; ni < 4; ni++) \
      bfr[ni] = *(const short8*)&(Bc_)[(wn * 128 + ni * 32 + l31) * 64 + so]; \
    _Pragma("unroll") \
    for (int mi = 0; mi < 4; mi++) \
      _Pragma("unroll") \
      for (int ni = 0; ni < 4; ni++) \
        acc[mi][ni] = __builtin_amdgcn_mfma_f32_32x32x16_bf16(af[mi], bfr[ni], acc[mi][ni], 0, 0, 0); \
  }

#define KLOOP(SA, SB) \
  STG(0, SA, SB) \
  asm volatile("s_waitcnt vmcnt(0)" ::: "memory"); \
  __builtin_amdgcn_s_barrier(); \
  asm volatile("" ::: "memory"); \
  _Pragma("unroll 1") \
  for (int t = 0; t < NTK; ++t) { \
    if (t + 1 < NTK) STG(t + 1, SA, SB) \
    const uint16_t* Ac_ = As[t & 1]; \
    const uint16_t* Bc_ = Bs[t & 1]; \
    COMPUTE(Ac_, Bc_) \
    asm volatile("s_waitcnt vmcnt(0)" ::: "memory"); \
    __builtin_amdgcn_s_barrier(); \
    asm volatile("" ::: "memory"); \
  }

// ---------------- GEMM1: qkv[16384,3072] = bf16( x @ Wqkv^T + bias ) ------
__global__ __launch_bounds__(256, 1) void gemm1(
    const uint16_t* __restrict__ A, const uint16_t* __restrict__ Bw,
    const float* __restrict__ bias, uint16_t* __restrict__ Cb)
{
  __shared__ __align__(16) uint16_t As[2][16384];   // 2 bufs x 256r x 64k
  __shared__ __align__(16) uint16_t Bs[2][16384];
  const int tid = threadIdx.x;
  const int wave = tid >> 6, lane = tid & 63;
  const int l31 = lane & 31, khalf = lane >> 5, r7 = l31 & 7;
  const int wm = wave & 1, wn = wave >> 1;          // 2x2 waves, 128x128 each
  const int id = blockIdx.x;
  const int xcd = id & 7, w = id >> 3;              // 768 blocks, 96/XCD
  const int tileM = ((w / 12) * 8 + xcd) * 256;     // 64 M-tiles
  const int tileN = (w % 12) * 256;                 // 12 N-tiles

  const int srow = wave * 8 + (lane >> 3);
  const int sk   = (lane & 7) ^ (lane >> 3);
  const uint16_t* gA = A  + (size_t)(tileM + srow) * 1024 + sk * 8;
  const uint16_t* gB = Bw + (size_t)(tileN + srow) * 1024 + sk * 8;

  floatx16 acc[4][4];
#pragma unroll
  for (int mi = 0; mi < 4; mi++)
#pragma unroll
    for (int ni = 0; ni < 4; ni++)
#pragma unroll
      for (int r = 0; r < 16; r++) acc[mi][ni][r] = 0.f;

  KLOOP(1024, 1024)

  // C/D layout 32x32: col = lane&31, row = (reg&3) + 8*(reg>>2) + 4*(lane>>5)
#pragma unroll
  for (int mi = 0; mi < 4; mi++) {
    const int rbase = tileM + wm * 128 + mi * 32 + 4 * khalf;
#pragma unroll
    for (int ni = 0; ni < 4; ni++) {
      const int col = tileN + wn * 128 + ni * 32 + l31;
      const float bv = bias[col];
#pragma unroll
      for (int reg = 0; reg < 16; reg++) {
        const int row = rbase + (reg & 3) + 8 * (reg >> 2);
        Cb[(size_t)row * 3072 + col] = f2bf(acc[mi][ni][reg] + bv);
      }
    }
  }
}

// ---------------- GEMM2: out[16384,1024] = invq[r]*(q @ W'^T) + b ---------
__global__ __launch_bounds__(256, 1) void gemm2(
    const uint16_t* __restrict__ qkv, const float* __restrict__ invq,
    const uint16_t* __restrict__ Wp, const float* __restrict__ bias,
    float* __restrict__ Cf)
{
  __shared__ __align__(16) uint16_t As[2][16384];
  __shared__ __align__(16) uint16_t Bs[2][16384];
  const int tid = threadIdx.x;
  const int wave = tid >> 6, lane = tid & 63;
  const int l31 = lane & 31, khalf = lane >> 5, r7 = l31 & 7;
  const int wm = wave & 1, wn = wave >> 1;
  // bijective XCD swizzle: 256 blocks = 8 XCDs x 32-chunk
  const int wid = (blockIdx.x & 7) * 32 + (blockIdx.x >> 3);
  const int tileM = (wid >> 2) * 256;               // 64 M-tiles
  const int tileN = (wid & 3) * 256;                // 4 N-tiles
  const int batch = tileM >> 12;

  const int srow = wave * 8 + (lane >> 3);
  const int sk   = (lane & 7) ^ (lane >> 3);
  const uint16_t* gA = qkv + (size_t)(tileM + srow) * 3072 + sk * 8;  // q slice
  const uint16_t* gB = Wp + ((size_t)batch << 20) + (size_t)(tileN + srow) * 1024 + sk * 8;

  floatx16 acc[4][4];
#pragma unroll
  for (int mi = 0; mi < 4; mi++)
#pragma unroll
    for (int ni = 0; ni < 4; ni++)
#pragma unroll
      for (int r = 0; r < 16; r++) acc[mi][ni][r] = 0.f;

  KLOOP(3072, 1024)

#pragma unroll
  for (int mi = 0; mi < 4; mi++) {
    const int rbase = tileM + wm * 128 + mi * 32 + 4 * khalf;
#pragma unroll
    for (int ni = 0; ni < 4; ni++) {
      const int col = tileN + wn * 128 + ni * 32 + l31;
      const float bv = bias[col];
#pragma unroll
      for (int reg = 0; reg < 16; reg++) {
        const int row = rbase + (reg & 3) + 8 * (reg >> 2);
        Cf[(size_t)row * 1024 + col] = fmaf(invq[row], acc[mi][ni][reg], bv);
      }
    }
  }
}

// ---------------- W'[b][n][k] = bf16( Wout[n][k] * kv[b][k] ) ----------------
__global__ __launch_bounds__(256) void scale_w(
    const uint16_t* __restrict__ wo, const float* __restrict__ kv,
    uint16_t* __restrict__ wp)
{
  int i = blockIdx.x * 256 + threadIdx.x;   // 4M elems / 8 = 512K threads
  int e = i << 3;
  int b = e >> 20;
  int k = e & 1023;
  uint4 w = *(const uint4*)(wo + (e & 0xFFFFF));
  float4 k0v = *(const float4*)(kv + (b << 10) + k);
  float4 k1v = *(const float4*)(kv + (b << 10) + k + 4);
  float wf[8]; upk8(w, wf);
  uint4 o;
  o.x = pack2(wf[0] * k0v.x, wf[1] * k0v.y);
  o.y = pack2(wf[2] * k0v.z, wf[3] * k0v.w);
  o.z = pack2(wf[4] * k1v.x, wf[5] * k1v.y);
  o.w = pack2(wf[6] * k1v.z, wf[7] * k1v.w);
  *(uint4*)(wp + e) = o;
}

// ---------------- mask layout detection ----------------
__global__ __launch_bounds__(256) void detect_mask(const unsigned char* __restrict__ m,
                                                   int* __restrict__ flag) {
  int i = blockIdx.x * blockDim.x + threadIdx.x;
  int v = ((i & 3) != 0) ? (int)m[i] : 0;
  unsigned long long b = __ballot(v != 0);
  if ((threadIdx.x & 63) == 0 && b) atomicOr(flag, 1);
}

// ---------------- per-row norms + kv reduction (512 blocks) ----------------
__global__ __launch_bounds__(256) void rownorm_kv(
    const uint16_t* __restrict__ qkv, const void* __restrict__ maskbuf,
    const int* __restrict__ flag, float* __restrict__ invq, float* __restrict__ kv)
{
  __shared__ float kvloc[1024];
  const int tid = threadIdx.x;
  for (int i = tid; i < 1024; i += 256) kvloc[i] = 0.f;
  __syncthreads();
  const int wave = tid >> 6, lane = tid & 63;
  const int b = blockIdx.x >> 7;
  const int chunk = blockIdx.x & 127;
  const int isU8 = *flag;
  const unsigned char* m8 = (const unsigned char*)maskbuf;
  const int* m32 = (const int*)maskbuf;

  float kvacc[16];
#pragma unroll
  for (int i = 0; i < 16; i++) kvacc[i] = 0.f;

  const int r0 = b * 4096 + chunk * 32 + wave * 8;
#pragma unroll 2
  for (int j = 0; j < 8; j++) {
    int r = r0 + j;
    const uint16_t* rp = qkv + (size_t)r * 3072;
    uint4 q0 = *(const uint4*)(rp + lane * 16);
    uint4 q1 = *(const uint4*)(rp + lane * 16 + 8);
    uint4 k0 = *(const uint4*)(rp + 1024 + lane * 16);
    uint4 k1 = *(const uint4*)(rp + 1024 + lane * 16 + 8);
    uint4 v0 = *(const uint4*)(rp + 2048 + lane * 16);
    uint4 v1 = *(const uint4*)(rp + 2048 + lane * 16 + 8);
    float qf[16], kf[16], vf[16];
    upk8(q0, qf); upk8(q1, qf + 8);
    upk8(k0, kf); upk8(k1, kf + 8);
    upk8(v0, vf); upk8(v1, vf + 8);
    float sq = 0.f, sk = 0.f;
#pragma unroll
    for (int i = 0; i < 16; i++) { sq = fmaf(qf[i], qf[i], sq); sk = fmaf(kf[i], kf[i], sk); }
    for (int off = 32; off; off >>= 1) { sq += __shfl_xor(sq, off); sk += __shfl_xor(sk, off); }
    float rq = rsqrtf(sq), rk = rsqrtf(sk);
    if (lane == 0) invq[r] = rq;
    int masked = isU8 ? (int)m8[r] : m32[r];
    if (!masked) {
#pragma unroll
      for (int i = 0; i < 16; i++) kvacc[i] = fmaf(kf[i] * rk, vf[i], kvacc[i]);
    }
  }
#pragma unroll
  for (int i = 0; i < 16; i++) atomicAdd(&kvloc[lane * 16 + i], kvacc[i]);
  __syncthreads();
  for (int i = tid; i < 1024; i += 256) atomicAdd(&kv[b * 1024 + i], kvloc[i]);
}

extern "C" void kernel_launch(void* const* d_in, const int* in_sizes, int n_in,
                              void* d_out, int out_size, void* d_ws, size_t ws_size,
                              hipStream_t stream) {
  const float* x     = (const float*)d_in[0];
  const void*  mask  = d_in[1];
  const float* W_qkv = (const float*)d_in[2];
  const float* b_qkv = (const float*)d_in[3];
  const float* W_out = (const float*)d_in[4];
  const float* b_out = (const float*)d_in[5];
  float* out = (float*)d_out;

  const int BT = 4 * 4096;  // 16384 rows
  const int D  = 1024;

  char* ws = (char*)d_ws;
  size_t off = 0;
  auto alloc = [&](size_t bytes) { size_t r = off; off += (bytes + 255) & ~(size_t)255; return r; };
  size_t o_xb   = alloc((size_t)BT * D * 2);        // x bf16
  size_t o_qkvb = alloc((size_t)BT * 3 * D * 2);    // qkv bf16
  size_t o_wq   = alloc((size_t)3 * D * D * 2);     // W_qkv bf16
  size_t o_wo   = alloc((size_t)D * D * 2);         // W_out bf16
  size_t o_wp   = alloc((size_t)4 * D * D * 2);     // W' = Wout*kv_b, per batch
  size_t o_kv   = alloc((size_t)4 * D * 4 + 256);   // kv (fp32) + flag
  size_t o_invq = alloc((size_t)BT * 4);            // 1/||q|| per row

  uint16_t* xb   = (uint16_t*)(ws + o_xb);
  uint16_t* qkvb = (uint16_t*)(ws + o_qkvb);
  uint16_t* wq   = (uint16_t*)(ws + o_wq);
  uint16_t* wo   = (uint16_t*)(ws + o_wo);
  uint16_t* wp   = (uint16_t*)(ws + o_wp);
  float*    kv   = (float*)(ws + o_kv);
  int*      flag = (int*)(ws + o_kv + (size_t)4 * D * 4);
  float*    invq = (float*)(ws + o_invq);

  hipMemsetAsync(ws + o_kv, 0, (size_t)4 * D * 4 + 256, stream);
  {
    int na = BT * D / 8, nb = 3 * D * D / 8, nc = D * D / 8;
    int tot = na + nb + nc;
    cvt3<<<dim3((tot + 255) / 256), 256, 0, stream>>>(x, xb, na, W_qkv, wq, nb, W_out, wo, nc);
  }
  detect_mask<<<dim3(64), 256, 0, stream>>>((const unsigned char*)mask, flag);
  gemm1<<<dim3(768), 256, 0, stream>>>(xb, wq, b_qkv, qkvb);
  rownorm_kv<<<dim3(512), 256, 0, stream>>>(qkvb, mask, flag, invq, kv);
  scale_w<<<dim3(4 * D * D / 8 / 256), 256, 0, stream>>>(wo, kv, wp);
  gemm2<<<dim3(256), 256, 0, stream>>>(qkvb, invq, wp, b_out, out);
}

// Round 6
// 317.231 us; speedup vs baseline: 1.1147x; 1.1147x over previous
//
#include <hip/hip_runtime.h>
#include <stdint.h>

// HydraAttention on MI355X (gfx950), R10.
// R9 failed correctness (absmax 0.35): the host-side isU8 guess from
// in_sizes misread the mask layout (in_sizes is element count; mask is
// stored as i32 words). Restored the harness-verified runtime detect_mask
// from R5. GEMM geometry (128x256 tile, 4 waves x 64x128 out, R5-style
// compiler-scheduled loop) retained for a clean measurement:
// LDS:MFMA ratio 2.19 -> 1.64, cap on MfmaUtil 46% -> 61%.
// Identity: out = invq[r] * (q @ (Wout*kv_b)^T) + b.

typedef short  short8   __attribute__((ext_vector_type(8)));
typedef float  floatx16 __attribute__((ext_vector_type(16)));

__device__ __forceinline__ void async16(const void* g, void* l) {
  __builtin_amdgcn_global_load_lds((const __attribute__((address_space(1))) void*)g,
                                   (__attribute__((address_space(3))) void*)l, 16, 0, 0);
}

__device__ __forceinline__ uint16_t f2bf(float f) {  // RNE fp32->bf16
  union { float f; uint32_t u; } x; x.f = f;
  uint32_t u = x.u;
  return (uint16_t)((u + 0x7fffu + ((u >> 16) & 1u)) >> 16);
}
__device__ __forceinline__ float bf2f(uint16_t h) {
  union { uint32_t u; float f; } x; x.u = ((uint32_t)h) << 16; return x.f;
}
__device__ __forceinline__ uint32_t pack2(float a, float b) {
  return (uint32_t)f2bf(a) | ((uint32_t)f2bf(b) << 16);
}
__device__ __forceinline__ void upk8(uint4 u, float* f) {
  f[0]=bf2f((uint16_t)u.x); f[1]=bf2f((uint16_t)(u.x>>16));
  f[2]=bf2f((uint16_t)u.y); f[3]=bf2f((uint16_t)(u.y>>16));
  f[4]=bf2f((uint16_t)u.z); f[5]=bf2f((uint16_t)(u.z>>16));
  f[6]=bf2f((uint16_t)u.w); f[7]=bf2f((uint16_t)(u.w>>16));
}

// ---------------- fused fp32->bf16 convert of 2 buffers ----------------
__global__ __launch_bounds__(256) void cvt2(
    const float* __restrict__ a, uint16_t* __restrict__ ao, int na,
    const float* __restrict__ b, uint16_t* __restrict__ bo, int nb) {
  int i = blockIdx.x * 256 + threadIdx.x;
  const float* in; uint16_t* out; int j = i;
  if (j < na) { in = a; out = ao; }
  else { j -= na; if (j >= nb) return; in = b; out = bo; }
  const float4* p = (const float4*)in;
  float4 u = p[(size_t)j * 2], v = p[(size_t)j * 2 + 1];
  uint4 o;
  o.x = pack2(u.x, u.y); o.y = pack2(u.z, u.w);
  o.z = pack2(v.x, v.y); o.w = pack2(v.z, v.w);
  ((uint4*)out)[j] = o;
}

// ---------------- GEMM1: qkv[16384,3072] = bf16( x @ Wqkv^T + bias ) ------
// 128x256 tile, BK=64, single-buffered LDS (48 KiB), 4 waves (2M x 2N),
// per-wave output 64x128 (acc 2x4 of 32x32). R5 schedule style: stage ->
// sync -> compute -> sync; compiler does all fine-grained scheduling.
__global__ __launch_bounds__(256, 2) void gemm1(
    const uint16_t* __restrict__ A, const uint16_t* __restrict__ Bw,
    const float* __restrict__ bias, uint16_t* __restrict__ Cb)
{
  __shared__ __align__(16) uint16_t As[128 * 64];   // 16 KiB
  __shared__ __align__(16) uint16_t Bs[256 * 64];   // 32 KiB
  const int tid = threadIdx.x;
  const int wave = tid >> 6, lane = tid & 63;
  const int l31 = lane & 31, khalf = lane >> 5;
  const int wm = wave & 1, wn = wave >> 1;
  // bijective XCD swizzle: 1536 blocks = 8 XCDs x 192; N-panel = 128 wgids
  const int wgid = (blockIdx.x & 7) * 192 + (blockIdx.x >> 3);
  const int tileM = (wgid & 127) * 128;             // 128 M-tiles
  const int tileN = (wgid >> 7) * 256;              // 12 N-tiles

  const int srow = wave * 8 + (lane >> 3);          // 32 rows per s-step
  const int skc  = (lane & 7) ^ (lane >> 3);        // pre-swizzled source slot
  const uint16_t* gA = A  + (size_t)(tileM + srow) * 1024 + skc * 8;
  const uint16_t* gB = Bw + (size_t)(tileN + srow) * 1024 + skc * 8;
  char* lA = (char*)As + wave * 1024;
  char* lB = (char*)Bs + wave * 1024;

  floatx16 acc[2][4];
#pragma unroll
  for (int mi = 0; mi < 2; mi++)
#pragma unroll
    for (int ni = 0; ni < 4; ni++)
#pragma unroll
      for (int r = 0; r < 16; r++) acc[mi][ni][r] = 0.f;

  const int arow0 = wm * 64 + l31;
  const int brow0 = wn * 128 + l31;

  for (int k0 = 0; k0 < 1024; k0 += 64) {
#pragma unroll
    for (int s = 0; s < 4; s++)
      async16(gA + k0 + (size_t)s * 32 * 1024, lA + s * 4096);
#pragma unroll
    for (int s = 0; s < 8; s++)
      async16(gB + k0 + (size_t)s * 32 * 1024, lB + s * 4096);
    __syncthreads();
#pragma unroll
    for (int ks = 0; ks < 4; ks++) {
      const int kc = khalf + ks * 2;
      short8 af[2], bfr[4];
#pragma unroll
      for (int mi = 0; mi < 2; mi++) {
        int r = arow0 + mi * 32;
        af[mi] = *(const short8*)&As[(r * 8 + (kc ^ (r & 7))) * 8];
      }
#pragma unroll
      for (int ni = 0; ni < 4; ni++) {
        int r = brow0 + ni * 32;
        bfr[ni] = *(const short8*)&Bs[(r * 8 + (kc ^ (r & 7))) * 8];
      }
#pragma unroll
      for (int mi = 0; mi < 2; mi++)
#pragma unroll
        for (int ni = 0; ni < 4; ni++)
          acc[mi][ni] = __builtin_amdgcn_mfma_f32_32x32x16_bf16(af[mi], bfr[ni], acc[mi][ni], 0, 0, 0);
    }
    __syncthreads();
  }

  // C/D layout 32x32: col = lane&31, row = (reg&3) + 8*(reg>>2) + 4*(lane>>5)
#pragma unroll
  for (int mi = 0; mi < 2; mi++) {
    const int rbase = tileM + wm * 64 + mi * 32 + 4 * khalf;
#pragma unroll
    for (int ni = 0; ni < 4; ni++) {
      const int col = tileN + wn * 128 + ni * 32 + l31;
      const float bv = bias[col];
#pragma unroll
      for (int reg = 0; reg < 16; reg++) {
        const int row = rbase + (reg & 3) + 8 * (reg >> 2);
        Cb[(size_t)row * 3072 + col] = f2bf(acc[mi][ni][reg] + bv);
      }
    }
  }
}

// ---------------- GEMM2: out[16384,1024] = invq[r]*(q @ W'^T) + b ---------
__global__ __launch_bounds__(256, 2) void gemm2(
    const uint16_t* __restrict__ qkv, const float* __restrict__ invq,
    const uint16_t* __restrict__ Wp, const float* __restrict__ bias,
    float* __restrict__ Cf)
{
  __shared__ __align__(16) uint16_t As[128 * 64];
  __shared__ __align__(16) uint16_t Bs[256 * 64];
  const int tid = threadIdx.x;
  const int wave = tid >> 6, lane = tid & 63;
  const int l31 = lane & 31, khalf = lane >> 5;
  const int wm = wave & 1, wn = wave >> 1;
  // bijective XCD swizzle: 512 blocks = 8 XCDs x 64; N-panel = 128 wgids
  const int wgid = (blockIdx.x & 7) * 64 + (blockIdx.x >> 3);
  const int tileM = (wgid & 127) * 128;             // 128 M-tiles
  const int tileN = (wgid >> 7) * 256;              // 4 N-tiles
  const int batch = tileM >> 12;

  const int srow = wave * 8 + (lane >> 3);
  const int skc  = (lane & 7) ^ (lane >> 3);
  const uint16_t* gA = qkv + (size_t)(tileM + srow) * 3072 + skc * 8;  // q slice
  const uint16_t* gB = Wp + ((size_t)batch << 20) + (size_t)(tileN + srow) * 1024 + skc * 8;
  char* lA = (char*)As + wave * 1024;
  char* lB = (char*)Bs + wave * 1024;

  floatx16 acc[2][4];
#pragma unroll
  for (int mi = 0; mi < 2; mi++)
#pragma unroll
    for (int ni = 0; ni < 4; ni++)
#pragma unroll
      for (int r = 0; r < 16; r++) acc[mi][ni][r] = 0.f;

  const int arow0 = wm * 64 + l31;
  const int brow0 = wn * 128 + l31;

  for (int k0 = 0; k0 < 1024; k0 += 64) {
#pragma unroll
    for (int s = 0; s < 4; s++)
      async16(gA + k0 + (size_t)s * 32 * 3072, lA + s * 4096);
#pragma unroll
    for (int s = 0; s < 8; s++)
      async16(gB + k0 + (size_t)s * 32 * 1024, lB + s * 4096);
    __syncthreads();
#pragma unroll
    for (int ks = 0; ks < 4; ks++) {
      const int kc = khalf + ks * 2;
      short8 af[2], bfr[4];
#pragma unroll
      for (int mi = 0; mi < 2; mi++) {
        int r = arow0 + mi * 32;
        af[mi] = *(const short8*)&As[(r * 8 + (kc ^ (r & 7))) * 8];
      }
#pragma unroll
      for (int ni = 0; ni < 4; ni++) {
        int r = brow0 + ni * 32;
        bfr[ni] = *(const short8*)&Bs[(r * 8 + (kc ^ (r & 7))) * 8];
      }
#pragma unroll
      for (int mi = 0; mi < 2; mi++)
#pragma unroll
        for (int ni = 0; ni < 4; ni++)
          acc[mi][ni] = __builtin_amdgcn_mfma_f32_32x32x16_bf16(af[mi], bfr[ni], acc[mi][ni], 0, 0, 0);
    }
    __syncthreads();
  }

#pragma unroll
  for (int mi = 0; mi < 2; mi++) {
    const int rbase = tileM + wm * 64 + mi * 32 + 4 * khalf;
#pragma unroll
    for (int ni = 0; ni < 4; ni++) {
      const int col = tileN + wn * 128 + ni * 32 + l31;
      const float bv = bias[col];
#pragma unroll
      for (int reg = 0; reg < 16; reg++) {
        const int row = rbase + (reg & 3) + 8 * (reg >> 2);
        Cf[(size_t)row * 1024 + col] = fmaf(invq[row], acc[mi][ni][reg], bv);
      }
    }
  }
}

// -------- W'[b][n][k] = bf16( Wout[n][k] * kv[b][k] ), fp32 Wout ---------
__global__ __launch_bounds__(256) void scale_w(
    const float* __restrict__ wo, const float* __restrict__ kv,
    uint16_t* __restrict__ wp)
{
  int i = blockIdx.x * 256 + threadIdx.x;   // 4M elems / 8 = 512K threads
  int e = i << 3;
  int b = e >> 20;
  int k = e & 1023;
  float4 w0 = *(const float4*)(wo + (e & 0xFFFFF));
  float4 w1 = *(const float4*)(wo + (e & 0xFFFFF) + 4);
  float4 k0v = *(const float4*)(kv + (b << 10) + k);
  float4 k1v = *(const float4*)(kv + (b << 10) + k + 4);
  uint4 o;
  o.x = pack2(w0.x * k0v.x, w0.y * k0v.y);
  o.y = pack2(w0.z * k0v.z, w0.w * k0v.w);
  o.z = pack2(w1.x * k1v.x, w1.y * k1v.y);
  o.w = pack2(w1.z * k1v.z, w1.w * k1v.w);
  *(uint4*)(wp + e) = o;
}

// ---------------- mask layout detection (harness-verified, from R5) -------
__global__ __launch_bounds__(256) void detect_mask(const unsigned char* __restrict__ m,
                                                   int* __restrict__ flag) {
  int i = blockIdx.x * blockDim.x + threadIdx.x;
  int v = ((i & 3) != 0) ? (int)m[i] : 0;
  unsigned long long b = __ballot(v != 0);
  if ((threadIdx.x & 63) == 0 && b) atomicOr(flag, 1);
}

// ---------------- per-row norms + kv reduction (512 blocks) ----------------
__global__ __launch_bounds__(256) void rownorm_kv(
    const uint16_t* __restrict__ qkv, const void* __restrict__ maskbuf,
    const int* __restrict__ flag, float* __restrict__ invq, float* __restrict__ kv)
{
  __shared__ float kvloc[1024];
  const int tid = threadIdx.x;
  for (int i = tid; i < 1024; i += 256) kvloc[i] = 0.f;
  __syncthreads();
  const int wave = tid >> 6, lane = tid & 63;
  const int b = blockIdx.x >> 7;
  const int chunk = blockIdx.x & 127;
  const int isU8 = *flag;
  const unsigned char* m8 = (const unsigned char*)maskbuf;
  const int* m32 = (const int*)maskbuf;

  float kvacc[16];
#pragma unroll
  for (int i = 0; i < 16; i++) kvacc[i] = 0.f;

  const int r0 = b * 4096 + chunk * 32 + wave * 8;
#pragma unroll 2
  for (int j = 0; j < 8; j++) {
    int r = r0 + j;
    const uint16_t* rp = qkv + (size_t)r * 3072;
    uint4 q0 = *(const uint4*)(rp + lane * 16);
    uint4 q1 = *(const uint4*)(rp + lane * 16 + 8);
    uint4 k0 = *(const uint4*)(rp + 1024 + lane * 16);
    uint4 k1 = *(const uint4*)(rp + 1024 + lane * 16 + 8);
    uint4 v0 = *(const uint4*)(rp + 2048 + lane * 16);
    uint4 v1 = *(const uint4*)(rp + 2048 + lane * 16 + 8);
    float qf[16], kf[16], vf[16];
    upk8(q0, qf); upk8(q1, qf + 8);
    upk8(k0, kf); upk8(k1, kf + 8);
    upk8(v0, vf); upk8(v1, vf + 8);
    float sq = 0.f, sk = 0.f;
#pragma unroll
    for (int i = 0; i < 16; i++) { sq = fmaf(qf[i], qf[i], sq); sk = fmaf(kf[i], kf[i], sk); }
    for (int off = 32; off; off >>= 1) { sq += __shfl_xor(sq, off); sk += __shfl_xor(sk, off); }
    float rq = rsqrtf(sq), rk = rsqrtf(sk);
    if (lane == 0) invq[r] = rq;
    int masked = isU8 ? (int)m8[r] : m32[r];
    if (!masked) {
#pragma unroll
      for (int i = 0; i < 16; i++) kvacc[i] = fmaf(kf[i] * rk, vf[i], kvacc[i]);
    }
  }
#pragma unroll
  for (int i = 0; i < 16; i++) atomicAdd(&kvloc[lane * 16 + i], kvacc[i]);
  __syncthreads();
  for (int i = tid; i < 1024; i += 256) atomicAdd(&kv[b * 1024 + i], kvloc[i]);
}

extern "C" void kernel_launch(void* const* d_in, const int* in_sizes, int n_in,
                              void* d_out, int out_size, void* d_ws, size_t ws_size,
                              hipStream_t stream) {
  const float* x     = (const float*)d_in[0];
  const void*  mask  = d_in[1];
  const float* W_qkv = (const float*)d_in[2];
  const float* b_qkv = (const float*)d_in[3];
  const float* W_out = (const float*)d_in[4];
  const float* b_out = (const float*)d_in[5];
  float* out = (float*)d_out;

  const int BT = 4 * 4096;  // 16384 rows
  const int D  = 1024;

  char* ws = (char*)d_ws;
  size_t off = 0;
  auto alloc = [&](size_t bytes) { size_t r = off; off += (bytes + 255) & ~(size_t)255; return r; };
  size_t o_xb   = alloc((size_t)BT * D * 2);        // x bf16
  size_t o_qkvb = alloc((size_t)BT * 3 * D * 2);    // qkv bf16
  size_t o_wq   = alloc((size_t)3 * D * D * 2);     // W_qkv bf16
  size_t o_wp   = alloc((size_t)4 * D * D * 2);     // W' = Wout*kv_b, per batch
  size_t o_kv   = alloc((size_t)4 * D * 4 + 256);   // kv (fp32) + flag
  size_t o_invq = alloc((size_t)BT * 4);            // 1/||q|| per row

  uint16_t* xb   = (uint16_t*)(ws + o_xb);
  uint16_t* qkvb = (uint16_t*)(ws + o_qkvb);
  uint16_t* wq   = (uint16_t*)(ws + o_wq);
  uint16_t* wp   = (uint16_t*)(ws + o_wp);
  float*    kv   = (float*)(ws + o_kv);
  int*      flag = (int*)(ws + o_kv + (size_t)4 * D * 4);
  float*    invq = (float*)(ws + o_invq);

  hipMemsetAsync(ws + o_kv, 0, (size_t)4 * D * 4 + 256, stream);
  {
    int na = BT * D / 8, nb = 3 * D * D / 8;
    int tot = na + nb;
    cvt2<<<dim3((tot + 255) / 256), 256, 0, stream>>>(x, xb, na, W_qkv, wq, nb);
  }
  detect_mask<<<dim3(64), 256, 0, stream>>>((const unsigned char*)mask, flag);
  gemm1<<<dim3(1536), 256, 0, stream>>>(xb, wq, b_qkv, qkvb);
  rownorm_kv<<<dim3(512), 256, 0, stream>>>(qkvb, mask, flag, invq, kv);
  scale_w<<<dim3(4 * D * D / 8 / 256), 256, 0, stream>>>(W_out, kv, wp);
  gemm2<<<dim3(512), 256, 0, stream>>>(qkvb, invq, wp, b_out, out);
}